// Round 1
// baseline (196.164 us; speedup 1.0000x reference)
//
#include <hip/hip_runtime.h>

#define B_     16
#define D_     256
#define HEADS_ 8
#define N_     32
#define H_     56
#define W_     56
#define L_     3136
#define BL_    (B_ * L_)   // 50176 flattened (b,l) columns

typedef short short8 __attribute__((ext_vector_type(8)));
typedef float f32x4  __attribute__((ext_vector_type(4)));

__device__ __forceinline__ unsigned short f2bf(float f) {
    union { float f; unsigned u; } c; c.f = f;
    unsigned u = c.u;
    u += 0x7fffu + ((u >> 16) & 1u);   // RNE
    return (unsigned short)(u >> 16);
}

// async global -> LDS, 16B per lane. LDS dest = wave-uniform base + lane*16.
#define GL2L(g, l) __builtin_amdgcn_global_load_lds( \
    (const __attribute__((address_space(1))) void*)(g), \
    (__attribute__((address_space(3))) void*)(l), 16, 0, 0)

// ---------------------------------------------------------------------------
// Wv, Wproj fp32 -> bf16; blockIdx.y==2 computes q~[b,h,c] = sum_n q[b,hn]*Wk[hn,c]
// ---------------------------------------------------------------------------
__global__ __launch_bounds__(256) void convert_w_kernel(
    const float* __restrict__ Wv, const float* __restrict__ Wproj,
    const float* __restrict__ Wk, const float* __restrict__ q,
    unsigned short* __restrict__ Wvb, unsigned short* __restrict__ Wpb,
    float* __restrict__ qt)
{
    if (blockIdx.y < 2) {
        const float* src   = (blockIdx.y == 0) ? Wv  : Wproj;
        unsigned short* dst = (blockIdx.y == 0) ? Wvb : Wpb;
        const int i = (blockIdx.x * 256 + threadIdx.x) * 4;
        float4 v = *(const float4*)(src + i);
        uint2 o;
        o.x = (unsigned)f2bf(v.x) | ((unsigned)f2bf(v.y) << 16);
        o.y = (unsigned)f2bf(v.z) | ((unsigned)f2bf(v.w) << 16);
        *(uint2*)(dst + i) = o;
    } else {
        // 64 blocks: b = bx>>2, heads {(bx&3)*2, +1}; thread = c
        const int b  = blockIdx.x >> 2;
        const int h0 = (blockIdx.x & 3) * 2;
        const int c  = threadIdx.x;
#pragma unroll
        for (int hh = 0; hh < 2; ++hh) {
            const int h = h0 + hh;
            const float* qb = q  + b * D_ + h * N_;
            const float* wr = Wk + (size_t)(h * N_) * D_ + c;
            float acc = 0.f;
#pragma unroll 8
            for (int n = 0; n < N_; ++n)
                acc = fmaf(qb[n], wr[(size_t)n * D_], acc);
            qt[((size_t)b * HEADS_ + h) * D_ + c] = acc;
        }
    }
}

// ---------------------------------------------------------------------------
// x [b][c][l] fp32 -> Xt [b][l][c] bf16, fused with S[b,h,l] = q~[b,h,:].x[b,:,l]
// Block: 64 l-cols x 256 c (4 LDS c-tiles). S accumulated in regs from the
// fp32 tile already in LDS (conflict-free: lane==l, stride-65 rows).
// ---------------------------------------------------------------------------
__global__ __launch_bounds__(256) void transpose_s_kernel(
    const float* __restrict__ x, const float* __restrict__ qt,
    unsigned short* __restrict__ Xt, float* __restrict__ S)
{
    __shared__ float tile[64][65];
    __shared__ float qs[2048];          // q~[h][c] for this batch
    __shared__ float Sred[4][8][64];

    const int bb = blockIdx.z;
    const int l0 = blockIdx.x * 64;
    const int t  = threadIdx.x;
    const int g4 = (t & 15) * 4;
    const int rr = t >> 4;
    const int sl = t & 63;              // lane = l within tile
    const int cq = t >> 6;              // wave = c quarter

    {   // load q~ for this batch (2048 floats)
        const float4* s4 = (const float4*)(qt + (size_t)bb * HEADS_ * D_);
        ((float4*)qs)[t]       = s4[t];
        ((float4*)qs)[t + 256] = s4[t + 256];
    }

    float sacc[8];
#pragma unroll
    for (int h = 0; h < 8; ++h) sacc[h] = 0.f;

    const float* xb = x + ((size_t)bb * D_) * L_ + l0;
    unsigned short* Xb = Xt + ((size_t)bb * L_ + l0) * D_;

    for (int ct = 0; ct < 4; ++ct) {
        const int c0 = ct * 64;
        float4 v[4];
#pragma unroll
        for (int i = 0; i < 4; ++i)
            v[i] = *(const float4*)(xb + (size_t)(c0 + rr + i * 16) * L_ + g4);
        __syncthreads();                 // previous tile's consumers done
#pragma unroll
        for (int i = 0; i < 4; ++i)
            *(float4*)&tile[rr + i * 16][g4] = v[i];
        __syncthreads();

        // transposed bf16 write
#pragma unroll
        for (int i = 0; i < 4; ++i) {
            const int l = rr + i * 16;
            uint2 o;
            o.x = (unsigned)f2bf(tile[g4 + 0][l]) | ((unsigned)f2bf(tile[g4 + 1][l]) << 16);
            o.y = (unsigned)f2bf(tile[g4 + 2][l]) | ((unsigned)f2bf(tile[g4 + 3][l]) << 16);
            *(uint2*)(Xb + (size_t)l * D_ + c0 + g4) = o;
        }

        // S partial: this wave handles c in [cq*16, cq*16+16)
#pragma unroll
        for (int cc = 0; cc < 16; ++cc) {
            const float xv = tile[cq * 16 + cc][sl];
            const int  ci = c0 + cq * 16 + cc;
#pragma unroll
            for (int h = 0; h < 8; ++h)
                sacc[h] = fmaf(qs[h * 256 + ci], xv, sacc[h]);
        }
    }

    __syncthreads();
#pragma unroll
    for (int h = 0; h < 8; ++h) Sred[cq][h][sl] = sacc[h];
    __syncthreads();
    {
        const int h0 = t >> 6;
#pragma unroll
        for (int r = 0; r < 2; ++r) {
            const int h = h0 + r * 4;
            const float s = Sred[0][h][sl] + Sred[1][h][sl] + Sred[2][h][sl] + Sred[3][h][sl];
            S[((size_t)bb * HEADS_ + h) * L_ + l0 + sl] = s;
        }
    }
}

// ---------------------------------------------------------------------------
// V = Wv @ x : 128(d) x 128(flat b*l) tile, BK=32, global_load_lds staging,
// double-buffered 2-phase (stage next || compute cur, one barrier per step).
// ---------------------------------------------------------------------------
__global__ __launch_bounds__(256) void gemm_v_mfma(
    const unsigned short* __restrict__ Xt, const unsigned short* __restrict__ Wvb,
    unsigned short* __restrict__ Vo)
{
    __shared__ unsigned short As[2][128 * 32];
    __shared__ unsigned short Bs[2][128 * 32];

    const int t = threadIdx.x;
    const int w = t >> 6, lane = t & 63, col = lane & 15, quad = lane >> 4;
    const int wr = w >> 1, wc = w & 1;
    const int n0 = blockIdx.x * 128;
    const int d0 = blockIdx.y * 128;
    const int srow = t >> 2;
    const int skc  = (t & 3) * 8;

    const unsigned short* Ag = Wvb + (size_t)(d0 + srow) * D_ + skc;
    const unsigned short* Bg = Xt + (size_t)(n0 + srow) * D_ + skc;

    f32x4 acc[4][4];
#pragma unroll
    for (int m = 0; m < 4; ++m)
#pragma unroll
        for (int n = 0; n < 4; ++n) acc[m][n] = (f32x4){0.f, 0.f, 0.f, 0.f};

    {   // prologue: stage kt=0 into buf 0
        char* An = (char*)&As[0][0] + w * 1024;
        char* Bn = (char*)&Bs[0][0] + w * 1024;
        GL2L(Ag, An);            GL2L(Ag + 64 * D_, An + 4096);
        GL2L(Bg, Bn);            GL2L(Bg + 64 * D_, Bn + 4096);
    }
    __syncthreads();

#pragma unroll
    for (int kt = 0; kt < 8; ++kt) {
        const int cur = kt & 1;
        if (kt < 7) {
            const int c1 = (kt + 1) * 32;
            char* An = (char*)&As[cur ^ 1][0] + w * 1024;
            char* Bn = (char*)&Bs[cur ^ 1][0] + w * 1024;
            GL2L(Ag + c1, An);           GL2L(Ag + 64 * D_ + c1, An + 4096);
            GL2L(Bg + c1, Bn);           GL2L(Bg + 64 * D_ + c1, Bn + 4096);
        }
        const unsigned short* Ab = &As[cur][0];
        const unsigned short* Bb = &Bs[cur][0];
        short8 af[4], bf[4];
#pragma unroll
        for (int m = 0; m < 4; ++m)
            af[m] = *(const short8*)(Ab + (wr * 64 + m * 16 + col) * 32 + quad * 8);
#pragma unroll
        for (int n = 0; n < 4; ++n)
            bf[n] = *(const short8*)(Bb + (wc * 64 + n * 16 + col) * 32 + quad * 8);
#pragma unroll
        for (int m = 0; m < 4; ++m)
#pragma unroll
            for (int n = 0; n < 4; ++n)
                acc[m][n] = __builtin_amdgcn_mfma_f32_16x16x32_bf16(af[m], bf[n], acc[m][n], 0, 0, 0);
        __syncthreads();
    }

#pragma unroll
    for (int n = 0; n < 4; ++n) {
        const unsigned flat = n0 + wc * 64 + n * 16 + col;
        const unsigned bq = flat / L_;
        const unsigned lq = flat - bq * L_;
        unsigned short* vout = Vo + (size_t)bq * D_ * L_ + lq;
#pragma unroll
        for (int m = 0; m < 4; ++m) {
            const int dbase = d0 + wr * 64 + m * 16 + quad * 4;
#pragma unroll
            for (int r = 0; r < 4; ++r)
                vout[(size_t)(dbase + r) * L_] = f2bf(acc[m][n][r]);
        }
    }
}

// ---------------------------------------------------------------------------
// attend: LDS-staged softmax + 9-tap weighted V sum (unchanged, verified)
// ---------------------------------------------------------------------------
__global__ __launch_bounds__(256) void attend_kernel(
    const float* __restrict__ S, const unsigned short* __restrict__ Vo,
    const float* __restrict__ pos_emb, const float* __restrict__ Wlin,
    unsigned short* __restrict__ Om)
{
    __shared__ unsigned short Vs[10][60][8];
    __shared__ float Ss[10][58];

    const int band = blockIdx.x;
    const int half = blockIdx.y;
    const int bh   = blockIdx.z;
    const int y0   = band * 8;
    const int t    = threadIdx.x;

    const float* Sb = S + (size_t)bh * L_;
    for (int wi = t; wi < 580; wi += 256) {
        const int row = wi / 58, c = wi - row * 58;
        const int gr = y0 - 1 + row, gc = c - 1;
        float v = 0.f;
        if (gr >= 0 && gr < H_ && gc >= 0 && gc < W_)
            v = Sb[gr * W_ + gc];
        Ss[row][c] = v;
    }

    const unsigned short* Vbase = Vo + ((size_t)bh * N_ + half * 8) * L_;
    for (int j = t; j < 560; j += 256) {
        const int ch = j & 7;
        const int rr = j >> 3;
        const int row = rr / 7, cg = rr - row * 7;
        const int gr = y0 - 1 + row;
        uint4 v = make_uint4(0u, 0u, 0u, 0u);
        if (gr >= 0 && gr < H_)
            v = *(const uint4*)(Vbase + (size_t)ch * L_ + gr * W_ + cg * 8);
        const unsigned short* hw = (const unsigned short*)&v;
        const int colb = cg * 8 + 1;
#pragma unroll
        for (int i = 0; i < 8; ++i)
            Vs[row][colb + i][ch] = hw[i];
    }
    if (t < 160) {
        const int row = t >> 4, side = (t >> 3) & 1, ch = t & 7;
        Vs[row][side ? 57 : 0][ch] = 0;
    }
    __syncthreads();

    const float scale = Wlin[0] + Wlin[1] + Wlin[2] + Wlin[3];
    const float pe0 = pos_emb[0], pe1 = pos_emb[1], pe2 = pos_emb[2];
    const float pe3 = pos_emb[3], pe4 = pos_emb[4];
    const float bias[9] = {pe0, pe1, pe2, pe1, pe2, pe3, pe2, pe3, pe4};

    for (int p = t; p < 448; p += 256) {
        const int yl = p / 56, xx = p - yl * 56;
        const int lr = yl + 1, lc = xx + 1;

        float lg[9], m = -1e30f;
#pragma unroll
        for (int dy = 0; dy < 3; ++dy)
#pragma unroll
            for (int dx = 0; dx < 3; ++dx) {
                const int k = dy * 3 + dx;
                lg[k] = Ss[lr - 1 + dy][lc - 1 + dx] + bias[k];
                m = fmaxf(m, lg[k]);
            }
        float ssum = 0.f;
#pragma unroll
        for (int k = 0; k < 9; ++k) { lg[k] = __expf(lg[k] - m); ssum += lg[k]; }
        const float inv = scale / ssum;

        float om[8] = {0.f, 0.f, 0.f, 0.f, 0.f, 0.f, 0.f, 0.f};
#pragma unroll
        for (int dy = 0; dy < 3; ++dy)
#pragma unroll
            for (int dx = 0; dx < 3; ++dx) {
                const float wk = lg[dy * 3 + dx] * inv;
                const uint4 v = *(const uint4*)&Vs[lr - 1 + dy][lc - 1 + dx][0];
                const unsigned* u = (const unsigned*)&v;
#pragma unroll
                for (int i = 0; i < 4; ++i) {
                    union { unsigned uu; float f; } lo, hi;
                    lo.uu = u[i] << 16;
                    hi.uu = u[i] & 0xffff0000u;
                    om[2 * i]     = fmaf(wk, lo.f, om[2 * i]);
                    om[2 * i + 1] = fmaf(wk, hi.f, om[2 * i + 1]);
                }
            }

        unsigned short ob[8];
#pragma unroll
        for (int i = 0; i < 8; ++i) ob[i] = f2bf(om[i]);
        const int l = (y0 + yl) * W_ + xx;
        *(uint4*)(Om + ((size_t)bh * L_ + l) * N_ + half * 8) = *(const uint4*)ob;
    }
}

// ---------------------------------------------------------------------------
// out = Wproj @ Om : same 128x128 2-phase structure; Om K-chunks are heads.
// ---------------------------------------------------------------------------
__global__ __launch_bounds__(256) void gemm_proj_mfma(
    const unsigned short* __restrict__ Om, const unsigned short* __restrict__ Wpb,
    float* __restrict__ Out)
{
    __shared__ unsigned short As[2][128 * 32];
    __shared__ unsigned short Bs[2][128 * 32];

    const int t = threadIdx.x;
    const int w = t >> 6, lane = t & 63, col = lane & 15, quad = lane >> 4;
    const int wr = w >> 1, wc = w & 1;
    const int n0 = blockIdx.x * 128;
    const int d0 = blockIdx.y * 128;
    const int srow = t >> 2;
    const int skc  = (t & 3) * 8;

    const unsigned short* Ag = Wpb + (size_t)(d0 + srow) * D_ + skc;
    const int f0 = n0 + srow;
    const unsigned b0q = (unsigned)f0 / L_, l0q = (unsigned)f0 - b0q * L_;
    const int f1 = f0 + 64;
    const unsigned b1q = (unsigned)f1 / L_, l1q = (unsigned)f1 - b1q * L_;
    const unsigned short* Bg0 = Om + ((size_t)(b0q * HEADS_) * L_ + l0q) * N_ + skc;
    const unsigned short* Bg1 = Om + ((size_t)(b1q * HEADS_) * L_ + l1q) * N_ + skc;
    const size_t kstride = (size_t)L_ * N_;

    f32x4 acc[4][4];
#pragma unroll
    for (int m = 0; m < 4; ++m)
#pragma unroll
        for (int n = 0; n < 4; ++n) acc[m][n] = (f32x4){0.f, 0.f, 0.f, 0.f};

    {   // prologue
        char* An = (char*)&As[0][0] + w * 1024;
        char* Bn = (char*)&Bs[0][0] + w * 1024;
        GL2L(Ag, An);            GL2L(Ag + 64 * D_, An + 4096);
        GL2L(Bg0, Bn);           GL2L(Bg1, Bn + 4096);
    }
    __syncthreads();

#pragma unroll
    for (int kt = 0; kt < 8; ++kt) {
        const int cur = kt & 1;
        if (kt < 7) {
            const int c1 = (kt + 1) * 32;
            char* An = (char*)&As[cur ^ 1][0] + w * 1024;
            char* Bn = (char*)&Bs[cur ^ 1][0] + w * 1024;
            GL2L(Ag + c1, An);                     GL2L(Ag + 64 * D_ + c1, An + 4096);
            GL2L(Bg0 + (kt + 1) * kstride, Bn);    GL2L(Bg1 + (kt + 1) * kstride, Bn + 4096);
        }
        const unsigned short* Ab = &As[cur][0];
        const unsigned short* Bb = &Bs[cur][0];
        short8 af[4], bf[4];
#pragma unroll
        for (int m = 0; m < 4; ++m)
            af[m] = *(const short8*)(Ab + (wr * 64 + m * 16 + col) * 32 + quad * 8);
#pragma unroll
        for (int n = 0; n < 4; ++n)
            bf[n] = *(const short8*)(Bb + (wc * 64 + n * 16 + col) * 32 + quad * 8);
#pragma unroll
        for (int m = 0; m < 4; ++m)
#pragma unroll
            for (int n = 0; n < 4; ++n)
                acc[m][n] = __builtin_amdgcn_mfma_f32_16x16x32_bf16(af[m], bf[n], acc[m][n], 0, 0, 0);
        __syncthreads();
    }

#pragma unroll
    for (int n = 0; n < 4; ++n) {
        const unsigned flat = n0 + wc * 64 + n * 16 + col;
        const unsigned bq = flat / L_;
        const unsigned lq = flat - bq * L_;
        float* oout = Out + (size_t)bq * D_ * L_ + lq;
#pragma unroll
        for (int m = 0; m < 4; ++m) {
            const int dbase = d0 + wr * 64 + m * 16 + quad * 4;
#pragma unroll
            for (int r = 0; r < 4; ++r)
                oout[(size_t)(dbase + r) * L_] = acc[m][n][r];
        }
    }
}

// ---------------------------------------------------------------------------
extern "C" void kernel_launch(void* const* d_in, const int* in_sizes, int n_in,
                              void* d_out, int out_size, void* d_ws, size_t ws_size,
                              hipStream_t stream)
{
    const float* x       = (const float*)d_in[0];
    const float* q       = (const float*)d_in[1];
    const float* Wk      = (const float*)d_in[2];
    const float* Wv      = (const float*)d_in[3];
    const float* pos_emb = (const float*)d_in[4];
    const float* Wlin    = (const float*)d_in[5];
    const float* Wproj   = (const float*)d_in[6];
    float* out = (float*)d_out;

    const size_t planeE = (size_t)B_ * D_ * L_;
    unsigned short* Xt  = (unsigned short*)d_ws;
    unsigned short* Vo  = Xt + planeE;
    unsigned short* Om  = Vo + planeE;
    unsigned short* Wvb = Om + planeE;
    unsigned short* Wpb = Wvb + D_ * D_;
    float*          S   = (float*)(Wpb + D_ * D_);
    float*          qt  = S + (size_t)B_ * HEADS_ * L_;

    convert_w_kernel<<<dim3(64, 3), 256, 0, stream>>>(Wv, Wproj, Wk, q, Wvb, Wpb, qt);
    transpose_s_kernel<<<dim3(49, 1, 16), 256, 0, stream>>>(x, qt, Xt, S);
    gemm_v_mfma<<<dim3(BL_ / 128, 2), 256, 0, stream>>>(Xt, Wvb, Vo);
    attend_kernel<<<dim3(7, 4, B_ * HEADS_), 256, 0, stream>>>(S, Vo, pos_emb, Wlin, Om);
    gemm_proj_mfma<<<dim3(BL_ / 128, 2), 256, 0, stream>>>(Om, Wpb, out);
}

// Round 2
// 191.088 us; speedup vs baseline: 1.0266x; 1.0266x over previous
//
#include <hip/hip_runtime.h>

#define B_     16
#define D_     256
#define HEADS_ 8
#define N_     32
#define H_     56
#define W_     56
#define L_     3136
#define BL_    (B_ * L_)   // 50176 flattened (b,l) columns

typedef short short8 __attribute__((ext_vector_type(8)));
typedef float f32x4  __attribute__((ext_vector_type(4)));

__device__ __forceinline__ unsigned short f2bf(float f) {
    union { float f; unsigned u; } c; c.f = f;
    unsigned u = c.u;
    u += 0x7fffu + ((u >> 16) & 1u);   // RNE
    return (unsigned short)(u >> 16);
}

// async global -> LDS, 16B per lane. LDS dest = wave-uniform base + lane*16.
#define GL2L(g, l) __builtin_amdgcn_global_load_lds( \
    (const __attribute__((address_space(1))) void*)(g), \
    (__attribute__((address_space(3))) void*)(l), 16, 0, 0)

// ---------------------------------------------------------------------------
// Wv, Wproj fp32 -> bf16; blockIdx.y==2 computes q~[b,h,c] = sum_n q[b,hn]*Wk[hn,c]
// ---------------------------------------------------------------------------
__global__ __launch_bounds__(256) void convert_w_kernel(
    const float* __restrict__ Wv, const float* __restrict__ Wproj,
    const float* __restrict__ Wk, const float* __restrict__ q,
    unsigned short* __restrict__ Wvb, unsigned short* __restrict__ Wpb,
    float* __restrict__ qt)
{
    if (blockIdx.y < 2) {
        const float* src   = (blockIdx.y == 0) ? Wv  : Wproj;
        unsigned short* dst = (blockIdx.y == 0) ? Wvb : Wpb;
        const int i = (blockIdx.x * 256 + threadIdx.x) * 4;
        float4 v = *(const float4*)(src + i);
        uint2 o;
        o.x = (unsigned)f2bf(v.x) | ((unsigned)f2bf(v.y) << 16);
        o.y = (unsigned)f2bf(v.z) | ((unsigned)f2bf(v.w) << 16);
        *(uint2*)(dst + i) = o;
    } else {
        const int b  = blockIdx.x >> 2;
        const int h0 = (blockIdx.x & 3) * 2;
        const int c  = threadIdx.x;
#pragma unroll
        for (int hh = 0; hh < 2; ++hh) {
            const int h = h0 + hh;
            const float* qb = q  + b * D_ + h * N_;
            const float* wr = Wk + (size_t)(h * N_) * D_ + c;
            float acc = 0.f;
#pragma unroll 8
            for (int n = 0; n < N_; ++n)
                acc = fmaf(qb[n], wr[(size_t)n * D_], acc);
            qt[((size_t)b * HEADS_ + h) * D_ + c] = acc;
        }
    }
}

// ---------------------------------------------------------------------------
// x [b][c][l] fp32 -> Xt [b][l][c] bf16  (round-0 proven form: 64x64 one-shot)
// ---------------------------------------------------------------------------
__global__ __launch_bounds__(256) void transpose_x_kernel(
    const float* __restrict__ x, unsigned short* __restrict__ Xt)
{
    __shared__ float tile[64][65];
    const int bb = blockIdx.z;
    const int c0 = blockIdx.y * 64;
    const int l0 = blockIdx.x * 64;
    const int t  = threadIdx.x;
    const int g4 = (t & 15) * 4;
    const int rr = t >> 4;

    const float* xb = x + ((size_t)bb * D_ + c0) * L_ + l0;
#pragma unroll
    for (int i = 0; i < 4; ++i) {
        const int c = rr + i * 16;
        float4 v = *(const float4*)(xb + (size_t)c * L_ + g4);
        *(float4*)&tile[c][g4] = v;
    }
    __syncthreads();
    unsigned short* Xb = Xt + ((size_t)bb * L_ + l0) * D_ + c0;
#pragma unroll
    for (int i = 0; i < 4; ++i) {
        const int l = rr + i * 16;
        uint2 o;
        o.x = (unsigned)f2bf(tile[g4 + 0][l]) | ((unsigned)f2bf(tile[g4 + 1][l]) << 16);
        o.y = (unsigned)f2bf(tile[g4 + 2][l]) | ((unsigned)f2bf(tile[g4 + 3][l]) << 16);
        *(uint2*)(Xb + (size_t)l * D_ + g4) = o;
    }
}

// ---------------------------------------------------------------------------
// S[b,h,l] = sum_c q~[b,h,c] * x[b,c,l]   (x is MALL-hot after transpose)
// Block: 64 l, 4 waves each own a 64-c quarter; LDS reduce.
// ---------------------------------------------------------------------------
__global__ __launch_bounds__(256) void s_kernel(
    const float* __restrict__ x, const float* __restrict__ qt,
    float* __restrict__ S)
{
    __shared__ float qs[HEADS_ * D_];      // 8 KB
    __shared__ float red[4][HEADS_][64];   // 8 KB

    const int bb = blockIdx.y;
    const int l0 = blockIdx.x * 64;
    const int t  = threadIdx.x;
    const int sl = t & 63;
    const int cq = t >> 6;

    {
        const float4* s4 = (const float4*)(qt + (size_t)bb * HEADS_ * D_);
        ((float4*)qs)[t]       = s4[t];
        ((float4*)qs)[t + 256] = s4[t + 256];
    }
    __syncthreads();

    float sacc[8];
#pragma unroll
    for (int h = 0; h < 8; ++h) sacc[h] = 0.f;

    const float* xb = x + (size_t)bb * D_ * L_ + l0 + sl;
#pragma unroll 4
    for (int c = cq * 64; c < cq * 64 + 64; ++c) {
        const float xv = xb[(size_t)c * L_];
#pragma unroll
        for (int h = 0; h < 8; ++h)
            sacc[h] = fmaf(qs[h * D_ + c], xv, sacc[h]);
    }

#pragma unroll
    for (int h = 0; h < 8; ++h) red[cq][h][sl] = sacc[h];
    __syncthreads();

    const int h0 = t >> 6;
#pragma unroll
    for (int r = 0; r < 2; ++r) {
        const int h = h0 + r * 4;
        const float s = red[0][h][sl] + red[1][h][sl] + red[2][h][sl] + red[3][h][sl];
        S[((size_t)bb * HEADS_ + h) * L_ + l0 + sl] = s;
    }
}

// ---------------------------------------------------------------------------
// V = Wv @ x : 128(d) x 128(flat b*l) tile, BK=32, global_load_lds staging,
// double-buffered 2-phase. Output layout Vo[b][h][l][32] (uint2 stores).
// ---------------------------------------------------------------------------
__global__ __launch_bounds__(256) void gemm_v_mfma(
    const unsigned short* __restrict__ Xt, const unsigned short* __restrict__ Wvb,
    unsigned short* __restrict__ Vo)
{
    __shared__ unsigned short As[2][128 * 32];
    __shared__ unsigned short Bs[2][128 * 32];

    const int t = threadIdx.x;
    const int w = t >> 6, lane = t & 63, col = lane & 15, quad = lane >> 4;
    const int wr = w >> 1, wc = w & 1;
    const int n0 = blockIdx.x * 128;
    const int d0 = blockIdx.y * 128;
    const int srow = t >> 2;
    const int skc  = (t & 3) * 8;

    const unsigned short* Ag = Wvb + (size_t)(d0 + srow) * D_ + skc;
    const unsigned short* Bg = Xt + (size_t)(n0 + srow) * D_ + skc;

    f32x4 acc[4][4];
#pragma unroll
    for (int m = 0; m < 4; ++m)
#pragma unroll
        for (int n = 0; n < 4; ++n) acc[m][n] = (f32x4){0.f, 0.f, 0.f, 0.f};

    {   // prologue: stage kt=0 into buf 0
        char* An = (char*)&As[0][0] + w * 1024;
        char* Bn = (char*)&Bs[0][0] + w * 1024;
        GL2L(Ag, An);            GL2L(Ag + 64 * D_, An + 4096);
        GL2L(Bg, Bn);            GL2L(Bg + 64 * D_, Bn + 4096);
    }
    __syncthreads();

#pragma unroll
    for (int kt = 0; kt < 8; ++kt) {
        const int cur = kt & 1;
        if (kt < 7) {
            const int c1 = (kt + 1) * 32;
            char* An = (char*)&As[cur ^ 1][0] + w * 1024;
            char* Bn = (char*)&Bs[cur ^ 1][0] + w * 1024;
            GL2L(Ag + c1, An);           GL2L(Ag + 64 * D_ + c1, An + 4096);
            GL2L(Bg + c1, Bn);           GL2L(Bg + 64 * D_ + c1, Bn + 4096);
        }
        const unsigned short* Ab = &As[cur][0];
        const unsigned short* Bb = &Bs[cur][0];
        short8 af[4], bf[4];
#pragma unroll
        for (int m = 0; m < 4; ++m)
            af[m] = *(const short8*)(Ab + (wr * 64 + m * 16 + col) * 32 + quad * 8);
#pragma unroll
        for (int n = 0; n < 4; ++n)
            bf[n] = *(const short8*)(Bb + (wc * 64 + n * 16 + col) * 32 + quad * 8);
#pragma unroll
        for (int m = 0; m < 4; ++m)
#pragma unroll
            for (int n = 0; n < 4; ++n)
                acc[m][n] = __builtin_amdgcn_mfma_f32_16x16x32_bf16(af[m], bf[n], acc[m][n], 0, 0, 0);
        __syncthreads();
    }

#pragma unroll
    for (int n = 0; n < 4; ++n) {
        const unsigned flat = n0 + wc * 64 + n * 16 + col;
        const unsigned bq = flat / L_;
        const unsigned lq = flat - bq * L_;
#pragma unroll
        for (int m = 0; m < 4; ++m) {
            const int d  = d0 + wr * 64 + m * 16 + quad * 4;
            const int h  = d >> 5;
            const int dn = d & 31;
            unsigned short ob[4];
#pragma unroll
            for (int r = 0; r < 4; ++r) ob[r] = f2bf(acc[m][n][r]);
            *(uint2*)(Vo + ((size_t)(bq * HEADS_ + h) * L_ + lq) * N_ + dn) =
                *(const uint2*)ob;
        }
    }
}

// ---------------------------------------------------------------------------
// attend: softmax + 9-tap weighted V sum. V layout [b][h][l][32]:
// staging is one 16B load + one 16B LDS write per position.
// ---------------------------------------------------------------------------
__global__ __launch_bounds__(256) void attend_kernel(
    const float* __restrict__ S, const unsigned short* __restrict__ Vo,
    const float* __restrict__ pos_emb, const float* __restrict__ Wlin,
    unsigned short* __restrict__ Om)
{
    __shared__ __align__(16) unsigned short Vs[10][60][8];
    __shared__ float Ss[10][58];

    const int band = blockIdx.x;
    const int half = blockIdx.y;
    const int bh   = blockIdx.z;
    const int y0   = band * 8;
    const int t    = threadIdx.x;

    const float* Sb = S + (size_t)bh * L_;
    for (int wi = t; wi < 580; wi += 256) {
        const int row = wi / 58, c = wi - row * 58;
        const int gr = y0 - 1 + row, gc = c - 1;
        float v = 0.f;
        if (gr >= 0 && gr < H_ && gc >= 0 && gc < W_)
            v = Sb[gr * W_ + gc];
        Ss[row][c] = v;
    }

    const unsigned short* Vbase = Vo + (size_t)bh * L_ * N_ + half * 8;
    for (int wi = t; wi < 580; wi += 256) {
        const int row = wi / 58, c = wi - row * 58;
        const int gr = y0 - 1 + row, gc = c - 1;
        uint4 v = make_uint4(0u, 0u, 0u, 0u);
        if (gr >= 0 && gr < H_ && gc >= 0 && gc < W_)
            v = *(const uint4*)(Vbase + (size_t)(gr * W_ + gc) * N_);
        *(uint4*)&Vs[row][c][0] = v;
    }
    __syncthreads();

    const float scale = Wlin[0] + Wlin[1] + Wlin[2] + Wlin[3];
    const float pe0 = pos_emb[0], pe1 = pos_emb[1], pe2 = pos_emb[2];
    const float pe3 = pos_emb[3], pe4 = pos_emb[4];
    const float bias[9] = {pe0, pe1, pe2, pe1, pe2, pe3, pe2, pe3, pe4};

    for (int p = t; p < 448; p += 256) {
        const int yl = p / 56, xx = p - yl * 56;
        const int lr = yl + 1, lc = xx + 1;

        float lg[9], m = -1e30f;
#pragma unroll
        for (int dy = 0; dy < 3; ++dy)
#pragma unroll
            for (int dx = 0; dx < 3; ++dx) {
                const int k = dy * 3 + dx;
                lg[k] = Ss[lr - 1 + dy][lc - 1 + dx] + bias[k];
                m = fmaxf(m, lg[k]);
            }
        float ssum = 0.f;
#pragma unroll
        for (int k = 0; k < 9; ++k) { lg[k] = __expf(lg[k] - m); ssum += lg[k]; }
        const float inv = scale / ssum;

        float om[8] = {0.f, 0.f, 0.f, 0.f, 0.f, 0.f, 0.f, 0.f};
#pragma unroll
        for (int dy = 0; dy < 3; ++dy)
#pragma unroll
            for (int dx = 0; dx < 3; ++dx) {
                const float wk = lg[dy * 3 + dx] * inv;
                const uint4 v = *(const uint4*)&Vs[lr - 1 + dy][lc - 1 + dx][0];
                const unsigned* u = (const unsigned*)&v;
#pragma unroll
                for (int i = 0; i < 4; ++i) {
                    union { unsigned uu; float f; } lo, hi;
                    lo.uu = u[i] << 16;
                    hi.uu = u[i] & 0xffff0000u;
                    om[2 * i]     = fmaf(wk, lo.f, om[2 * i]);
                    om[2 * i + 1] = fmaf(wk, hi.f, om[2 * i + 1]);
                }
            }

        unsigned short ob[8];
#pragma unroll
        for (int i = 0; i < 8; ++i) ob[i] = f2bf(om[i]);
        const int l = (y0 + yl) * W_ + xx;
        *(uint4*)(Om + ((size_t)bh * L_ + l) * N_ + half * 8) = *(const uint4*)ob;
    }
}

// ---------------------------------------------------------------------------
// out = Wproj @ Om : same 128x128 2-phase structure; Om K-chunks are heads.
// ---------------------------------------------------------------------------
__global__ __launch_bounds__(256) void gemm_proj_mfma(
    const unsigned short* __restrict__ Om, const unsigned short* __restrict__ Wpb,
    float* __restrict__ Out)
{
    __shared__ unsigned short As[2][128 * 32];
    __shared__ unsigned short Bs[2][128 * 32];

    const int t = threadIdx.x;
    const int w = t >> 6, lane = t & 63, col = lane & 15, quad = lane >> 4;
    const int wr = w >> 1, wc = w & 1;
    const int n0 = blockIdx.x * 128;
    const int d0 = blockIdx.y * 128;
    const int srow = t >> 2;
    const int skc  = (t & 3) * 8;

    const unsigned short* Ag = Wpb + (size_t)(d0 + srow) * D_ + skc;
    const int f0 = n0 + srow;
    const unsigned b0q = (unsigned)f0 / L_, l0q = (unsigned)f0 - b0q * L_;
    const int f1 = f0 + 64;
    const unsigned b1q = (unsigned)f1 / L_, l1q = (unsigned)f1 - b1q * L_;
    const unsigned short* Bg0 = Om + ((size_t)(b0q * HEADS_) * L_ + l0q) * N_ + skc;
    const unsigned short* Bg1 = Om + ((size_t)(b1q * HEADS_) * L_ + l1q) * N_ + skc;
    const size_t kstride = (size_t)L_ * N_;

    f32x4 acc[4][4];
#pragma unroll
    for (int m = 0; m < 4; ++m)
#pragma unroll
        for (int n = 0; n < 4; ++n) acc[m][n] = (f32x4){0.f, 0.f, 0.f, 0.f};

    {   // prologue
        char* An = (char*)&As[0][0] + w * 1024;
        char* Bn = (char*)&Bs[0][0] + w * 1024;
        GL2L(Ag, An);            GL2L(Ag + 64 * D_, An + 4096);
        GL2L(Bg0, Bn);           GL2L(Bg1, Bn + 4096);
    }
    __syncthreads();

#pragma unroll
    for (int kt = 0; kt < 8; ++kt) {
        const int cur = kt & 1;
        if (kt < 7) {
            const int c1 = (kt + 1) * 32;
            char* An = (char*)&As[cur ^ 1][0] + w * 1024;
            char* Bn = (char*)&Bs[cur ^ 1][0] + w * 1024;
            GL2L(Ag + c1, An);                     GL2L(Ag + 64 * D_ + c1, An + 4096);
            GL2L(Bg0 + (kt + 1) * kstride, Bn);    GL2L(Bg1 + (kt + 1) * kstride, Bn + 4096);
        }
        const unsigned short* Ab = &As[cur][0];
        const unsigned short* Bb = &Bs[cur][0];
        short8 af[4], bf[4];
#pragma unroll
        for (int m = 0; m < 4; ++m)
            af[m] = *(const short8*)(Ab + (wr * 64 + m * 16 + col) * 32 + quad * 8);
#pragma unroll
        for (int n = 0; n < 4; ++n)
            bf[n] = *(const short8*)(Bb + (wc * 64 + n * 16 + col) * 32 + quad * 8);
#pragma unroll
        for (int m = 0; m < 4; ++m)
#pragma unroll
            for (int n = 0; n < 4; ++n)
                acc[m][n] = __builtin_amdgcn_mfma_f32_16x16x32_bf16(af[m], bf[n], acc[m][n], 0, 0, 0);
        __syncthreads();
    }

#pragma unroll
    for (int n = 0; n < 4; ++n) {
        const unsigned flat = n0 + wc * 64 + n * 16 + col;
        const unsigned bq = flat / L_;
        const unsigned lq = flat - bq * L_;
        float* oout = Out + (size_t)bq * D_ * L_ + lq;
#pragma unroll
        for (int m = 0; m < 4; ++m) {
            const int dbase = d0 + wr * 64 + m * 16 + quad * 4;
#pragma unroll
            for (int r = 0; r < 4; ++r)
                oout[(size_t)(dbase + r) * L_] = acc[m][n][r];
        }
    }
}

// ---------------------------------------------------------------------------
extern "C" void kernel_launch(void* const* d_in, const int* in_sizes, int n_in,
                              void* d_out, int out_size, void* d_ws, size_t ws_size,
                              hipStream_t stream)
{
    const float* x       = (const float*)d_in[0];
    const float* q       = (const float*)d_in[1];
    const float* Wk      = (const float*)d_in[2];
    const float* Wv      = (const float*)d_in[3];
    const float* pos_emb = (const float*)d_in[4];
    const float* Wlin    = (const float*)d_in[5];
    const float* Wproj   = (const float*)d_in[6];
    float* out = (float*)d_out;

    const size_t planeE = (size_t)B_ * D_ * L_;
    unsigned short* Xt  = (unsigned short*)d_ws;
    unsigned short* Vo  = Xt + planeE;
    unsigned short* Om  = Vo + planeE;
    unsigned short* Wvb = Om + planeE;
    unsigned short* Wpb = Wvb + D_ * D_;
    float*          S   = (float*)(Wpb + D_ * D_);
    float*          qt  = S + (size_t)B_ * HEADS_ * L_;

    convert_w_kernel<<<dim3(64, 3), 256, 0, stream>>>(Wv, Wproj, Wk, q, Wvb, Wpb, qt);
    transpose_x_kernel<<<dim3(L_ / 64, D_ / 64, B_), 256, 0, stream>>>(x, Xt);
    s_kernel<<<dim3(L_ / 64, B_), 256, 0, stream>>>(x, qt, S);
    gemm_v_mfma<<<dim3(BL_ / 128, 2), 256, 0, stream>>>(Xt, Wvb, Vo);
    attend_kernel<<<dim3(7, 4, B_ * HEADS_), 256, 0, stream>>>(S, Vo, pos_emb, Wlin, Om);
    gemm_proj_mfma<<<dim3(BL_ / 128, 2), 256, 0, stream>>>(Om, Wpb, out);
}

// Round 3
// 177.246 us; speedup vs baseline: 1.1067x; 1.0781x over previous
//
#include <hip/hip_runtime.h>

#define B_     16
#define D_     256
#define HEADS_ 8
#define N_     32
#define H_     56
#define W_     56
#define L_     3136
#define BL_    (B_ * L_)   // 50176 flattened (b,l) columns

typedef short short8 __attribute__((ext_vector_type(8)));
typedef float f32x4  __attribute__((ext_vector_type(4)));

__device__ __forceinline__ unsigned short f2bf(float f) {
    union { float f; unsigned u; } c; c.f = f;
    unsigned u = c.u;
    u += 0x7fffu + ((u >> 16) & 1u);   // RNE
    return (unsigned short)(u >> 16);
}

// async global -> LDS, 16B per lane. LDS dest = wave-uniform base + lane*16.
#define GL2L(g, l) __builtin_amdgcn_global_load_lds( \
    (const __attribute__((address_space(1))) void*)(g), \
    (__attribute__((address_space(3))) void*)(l), 16, 0, 0)

// ---------------------------------------------------------------------------
// Wv, Wproj fp32 -> bf16; blockIdx.y==2 computes q~[b,h,c] = sum_n q[b,hn]*Wk[hn,c]
// ---------------------------------------------------------------------------
__global__ __launch_bounds__(256) void convert_w_kernel(
    const float* __restrict__ Wv, const float* __restrict__ Wproj,
    const float* __restrict__ Wk, const float* __restrict__ q,
    unsigned short* __restrict__ Wvb, unsigned short* __restrict__ Wpb,
    float* __restrict__ qt)
{
    if (blockIdx.y < 2) {
        const float* src   = (blockIdx.y == 0) ? Wv  : Wproj;
        unsigned short* dst = (blockIdx.y == 0) ? Wvb : Wpb;
        const int i = (blockIdx.x * 256 + threadIdx.x) * 4;
        float4 v = *(const float4*)(src + i);
        uint2 o;
        o.x = (unsigned)f2bf(v.x) | ((unsigned)f2bf(v.y) << 16);
        o.y = (unsigned)f2bf(v.z) | ((unsigned)f2bf(v.w) << 16);
        *(uint2*)(dst + i) = o;
    } else {
        const int b  = blockIdx.x >> 2;
        const int h0 = (blockIdx.x & 3) * 2;
        const int c  = threadIdx.x;
#pragma unroll
        for (int hh = 0; hh < 2; ++hh) {
            const int h = h0 + hh;
            const float* qb = q  + b * D_ + h * N_;
            const float* wr = Wk + (size_t)(h * N_) * D_ + c;
            float acc = 0.f;
#pragma unroll 8
            for (int n = 0; n < N_; ++n)
                acc = fmaf(qb[n], wr[(size_t)n * D_], acc);
            qt[((size_t)b * HEADS_ + h) * D_ + c] = acc;
        }
    }
}

// ---------------------------------------------------------------------------
// x [b][c][l] fp32 -> Xt [b][l][c] bf16  (round-0 proven form: 64x64 one-shot)
// ---------------------------------------------------------------------------
__global__ __launch_bounds__(256) void transpose_x_kernel(
    const float* __restrict__ x, unsigned short* __restrict__ Xt)
{
    __shared__ float tile[64][65];
    const int bb = blockIdx.z;
    const int c0 = blockIdx.y * 64;
    const int l0 = blockIdx.x * 64;
    const int t  = threadIdx.x;
    const int g4 = (t & 15) * 4;
    const int rr = t >> 4;

    const float* xb = x + ((size_t)bb * D_ + c0) * L_ + l0;
#pragma unroll
    for (int i = 0; i < 4; ++i) {
        const int c = rr + i * 16;
        float4 v = *(const float4*)(xb + (size_t)c * L_ + g4);
        *(float4*)&tile[c][g4] = v;
    }
    __syncthreads();
    unsigned short* Xb = Xt + ((size_t)bb * L_ + l0) * D_ + c0;
#pragma unroll
    for (int i = 0; i < 4; ++i) {
        const int l = rr + i * 16;
        uint2 o;
        o.x = (unsigned)f2bf(tile[g4 + 0][l]) | ((unsigned)f2bf(tile[g4 + 1][l]) << 16);
        o.y = (unsigned)f2bf(tile[g4 + 2][l]) | ((unsigned)f2bf(tile[g4 + 3][l]) << 16);
        *(uint2*)(Xb + (size_t)l * D_ + g4) = o;
    }
}

// ---------------------------------------------------------------------------
// S[b,h,l] = sum_c q~[b,h,c] * x[b,c,l]   (x is L3-hot after transpose)
// float4-per-lane: block covers 256 l, 4 waves each own a 64-c quarter.
// ---------------------------------------------------------------------------
__global__ __launch_bounds__(256) void s_kernel(
    const float* __restrict__ x, const float* __restrict__ qt,
    float* __restrict__ S)
{
    __shared__ float  qs[HEADS_ * D_];        // 8 KB
    __shared__ float4 red[4][HEADS_ * 64];    // 32 KB

    const int bb = blockIdx.y;
    const int l0 = blockIdx.x * 256;
    const int t  = threadIdx.x;
    const int sl = t & 63;
    const int cq = t >> 6;

    {
        const float4* s4 = (const float4*)(qt + (size_t)bb * HEADS_ * D_);
        ((float4*)qs)[t]       = s4[t];
        ((float4*)qs)[t + 256] = s4[t + 256];
    }
    __syncthreads();

    float4 sacc[8];
#pragma unroll
    for (int h = 0; h < 8; ++h) sacc[h] = (float4){0.f, 0.f, 0.f, 0.f};

    const int l = l0 + sl * 4;
    if (l < L_) {
        const float* xb = x + (size_t)bb * D_ * L_ + l;
#pragma unroll 4
        for (int c = cq * 64; c < cq * 64 + 64; ++c) {
            const float4 xv = *(const float4*)(xb + (size_t)c * L_);
#pragma unroll
            for (int h = 0; h < 8; ++h) {
                const float qv = qs[h * D_ + c];
                sacc[h].x = fmaf(qv, xv.x, sacc[h].x);
                sacc[h].y = fmaf(qv, xv.y, sacc[h].y);
                sacc[h].z = fmaf(qv, xv.z, sacc[h].z);
                sacc[h].w = fmaf(qv, xv.w, sacc[h].w);
            }
        }
    }

#pragma unroll
    for (int h = 0; h < 8; ++h) red[cq][h * 64 + sl] = sacc[h];
    __syncthreads();

    for (int j = t; j < 512; j += 256) {
        const int h = j >> 6, s = j & 63;
        const int lw = l0 + s * 4;
        if (lw < L_) {
            const float4 a = red[0][h * 64 + s];
            const float4 b = red[1][h * 64 + s];
            const float4 c = red[2][h * 64 + s];
            const float4 d = red[3][h * 64 + s];
            float4 o;
            o.x = a.x + b.x + c.x + d.x;
            o.y = a.y + b.y + c.y + d.y;
            o.z = a.z + b.z + c.z + d.z;
            o.w = a.w + b.w + c.w + d.w;
            *(float4*)(S + ((size_t)bb * HEADS_ + h) * L_ + lw) = o;
        }
    }
}

// ---------------------------------------------------------------------------
// V = Wv @ x : 128(d) x 128(flat b*l) tile, BK=32, global_load_lds staging,
// double-buffered 2-phase. Output layout Vo[b][h][l][32] (uint2 stores).
// ---------------------------------------------------------------------------
__global__ __launch_bounds__(256) void gemm_v_mfma(
    const unsigned short* __restrict__ Xt, const unsigned short* __restrict__ Wvb,
    unsigned short* __restrict__ Vo)
{
    __shared__ unsigned short As[2][128 * 32];
    __shared__ unsigned short Bs[2][128 * 32];

    const int t = threadIdx.x;
    const int w = t >> 6, lane = t & 63, col = lane & 15, quad = lane >> 4;
    const int wr = w >> 1, wc = w & 1;
    const int n0 = blockIdx.x * 128;
    const int d0 = blockIdx.y * 128;
    const int srow = t >> 2;
    const int skc  = (t & 3) * 8;

    const unsigned short* Ag = Wvb + (size_t)(d0 + srow) * D_ + skc;
    const unsigned short* Bg = Xt + (size_t)(n0 + srow) * D_ + skc;

    f32x4 acc[4][4];
#pragma unroll
    for (int m = 0; m < 4; ++m)
#pragma unroll
        for (int n = 0; n < 4; ++n) acc[m][n] = (f32x4){0.f, 0.f, 0.f, 0.f};

    {   // prologue: stage kt=0 into buf 0
        char* An = (char*)&As[0][0] + w * 1024;
        char* Bn = (char*)&Bs[0][0] + w * 1024;
        GL2L(Ag, An);            GL2L(Ag + 64 * D_, An + 4096);
        GL2L(Bg, Bn);            GL2L(Bg + 64 * D_, Bn + 4096);
    }
    __syncthreads();

#pragma unroll
    for (int kt = 0; kt < 8; ++kt) {
        const int cur = kt & 1;
        if (kt < 7) {
            const int c1 = (kt + 1) * 32;
            char* An = (char*)&As[cur ^ 1][0] + w * 1024;
            char* Bn = (char*)&Bs[cur ^ 1][0] + w * 1024;
            GL2L(Ag + c1, An);           GL2L(Ag + 64 * D_ + c1, An + 4096);
            GL2L(Bg + c1, Bn);           GL2L(Bg + 64 * D_ + c1, Bn + 4096);
        }
        const unsigned short* Ab = &As[cur][0];
        const unsigned short* Bb = &Bs[cur][0];
        short8 af[4], bf[4];
#pragma unroll
        for (int m = 0; m < 4; ++m)
            af[m] = *(const short8*)(Ab + (wr * 64 + m * 16 + col) * 32 + quad * 8);
#pragma unroll
        for (int n = 0; n < 4; ++n)
            bf[n] = *(const short8*)(Bb + (wc * 64 + n * 16 + col) * 32 + quad * 8);
#pragma unroll
        for (int m = 0; m < 4; ++m)
#pragma unroll
            for (int n = 0; n < 4; ++n)
                acc[m][n] = __builtin_amdgcn_mfma_f32_16x16x32_bf16(af[m], bf[n], acc[m][n], 0, 0, 0);
        __syncthreads();
    }

#pragma unroll
    for (int n = 0; n < 4; ++n) {
        const unsigned flat = n0 + wc * 64 + n * 16 + col;
        const unsigned bq = flat / L_;
        const unsigned lq = flat - bq * L_;
#pragma unroll
        for (int m = 0; m < 4; ++m) {
            const int d  = d0 + wr * 64 + m * 16 + quad * 4;
            const int h  = d >> 5;
            const int dn = d & 31;
            unsigned short ob[4];
#pragma unroll
            for (int r = 0; r < 4; ++r) ob[r] = f2bf(acc[m][n][r]);
            *(uint2*)(Vo + ((size_t)(bq * HEADS_ + h) * L_ + lq) * N_ + dn) =
                *(const uint2*)ob;
        }
    }
}

// ---------------------------------------------------------------------------
// attend v4: block = (8-row band, b*h), ALL 32 channels of the head.
// V staged as 600 positions x 64B in LDS with XOR chunk swizzle
// (sfc = fc ^ (pos&7)): conflict-free b128 reads, contiguous global loads.
// Softmax computed once per position.
// ---------------------------------------------------------------------------
__global__ __launch_bounds__(256) void attend_kernel(
    const float* __restrict__ S, const unsigned short* __restrict__ Vo,
    const float* __restrict__ pos_emb, const float* __restrict__ Wlin,
    unsigned short* __restrict__ Om)
{
    __shared__ __align__(16) unsigned short Vs[600 * 32];  // 37.5 KB swizzled
    __shared__ float Ss[10][58];                           // 2.3 KB

    const int band = blockIdx.x;   // 0..6
    const int bh   = blockIdx.y;   // 0..127
    const int y0   = band * 8;
    const int t    = threadIdx.x;

    // ---- stage S (10 x 58, zero halo) ----
    const float* Sb = S + (size_t)bh * L_;
    for (int wi = t; wi < 580; wi += 256) {
        const int row = wi / 58, c = wi - row * 58;
        const int gr = y0 - 1 + row, gc = c - 1;
        float v = 0.f;
        if (gr >= 0 && gr < H_ && gc >= 0 && gc < W_)
            v = Sb[gr * W_ + gc];
        Ss[row][c] = v;
    }

    // ---- stage V: 600 positions x 4 chunks of 16B, contiguous loads ----
    const unsigned short* Vbase = Vo + (size_t)bh * L_ * N_;
    for (int wi = t; wi < 2400; wi += 256) {
        const int p = wi >> 2, i = wi & 3;
        const int row = p / 60, cc = p - row * 60;
        const int gr = y0 - 1 + row, gc = cc - 1;
        uint4 v = make_uint4(0u, 0u, 0u, 0u);
        if (gr >= 0 && gr < H_ && gc >= 0 && gc < W_)
            v = *(const uint4*)(Vbase + (size_t)(gr * W_ + gc) * N_ + i * 8);
        const int sfc = wi ^ (p & 7);          // swizzled 16B-chunk index
        *(uint4*)(Vs + sfc * 8) = v;
    }
    __syncthreads();

    const float scale = Wlin[0] + Wlin[1] + Wlin[2] + Wlin[3];
    const float pe0 = pos_emb[0], pe1 = pos_emb[1], pe2 = pos_emb[2];
    const float pe3 = pos_emb[3], pe4 = pos_emb[4];
    const float bias[9] = {pe0, pe1, pe2, pe1, pe2, pe3, pe2, pe3, pe4};

    for (int idx = t; idx < 448; idx += 256) {
        const int yl = idx / 56, xx = idx - yl * 56;
        const int lr = yl + 1, lc = xx + 1;

        float lg[9], m = -1e30f;
#pragma unroll
        for (int dy = 0; dy < 3; ++dy)
#pragma unroll
            for (int dx = 0; dx < 3; ++dx) {
                const int k = dy * 3 + dx;
                lg[k] = Ss[lr - 1 + dy][lc - 1 + dx] + bias[k];
                m = fmaxf(m, lg[k]);
            }
        float ssum = 0.f;
#pragma unroll
        for (int k = 0; k < 9; ++k) { lg[k] = __expf(lg[k] - m); ssum += lg[k]; }
        const float inv = scale / ssum;

        float om[32];
#pragma unroll
        for (int i = 0; i < 32; ++i) om[i] = 0.f;

#pragma unroll
        for (int dy = 0; dy < 3; ++dy)
#pragma unroll
            for (int dx = 0; dx < 3; ++dx) {
                const float wk = lg[dy * 3 + dx] * inv;
                const int pos  = (lr - 1 + dy) * 60 + (lc - 1 + dx);
                const int base = pos * 4;
                const int msk  = pos & 7;
#pragma unroll
                for (int i = 0; i < 4; ++i) {
                    const int sfc = (base + i) ^ msk;
                    const uint4 v = *(const uint4*)(Vs + sfc * 8);
                    const unsigned* u = (const unsigned*)&v;
#pragma unroll
                    for (int j = 0; j < 4; ++j) {
                        union { unsigned uu; float f; } lo, hi;
                        lo.uu = u[j] << 16;
                        hi.uu = u[j] & 0xffff0000u;
                        om[i * 8 + 2 * j]     = fmaf(wk, lo.f, om[i * 8 + 2 * j]);
                        om[i * 8 + 2 * j + 1] = fmaf(wk, hi.f, om[i * 8 + 2 * j + 1]);
                    }
                }
            }

        unsigned short ob[32];
#pragma unroll
        for (int i = 0; i < 32; ++i) ob[i] = f2bf(om[i]);
        const int l = (y0 + yl) * W_ + xx;
        uint4* dst = (uint4*)(Om + ((size_t)bh * L_ + l) * N_);
        const uint4* sb = (const uint4*)ob;
#pragma unroll
        for (int i = 0; i < 4; ++i) dst[i] = sb[i];
    }
}

// ---------------------------------------------------------------------------
// out = Wproj @ Om : same 128x128 2-phase structure; Om K-chunks are heads.
// ---------------------------------------------------------------------------
__global__ __launch_bounds__(256) void gemm_proj_mfma(
    const unsigned short* __restrict__ Om, const unsigned short* __restrict__ Wpb,
    float* __restrict__ Out)
{
    __shared__ unsigned short As[2][128 * 32];
    __shared__ unsigned short Bs[2][128 * 32];

    const int t = threadIdx.x;
    const int w = t >> 6, lane = t & 63, col = lane & 15, quad = lane >> 4;
    const int wr = w >> 1, wc = w & 1;
    const int n0 = blockIdx.x * 128;
    const int d0 = blockIdx.y * 128;
    const int srow = t >> 2;
    const int skc  = (t & 3) * 8;

    const unsigned short* Ag = Wpb + (size_t)(d0 + srow) * D_ + skc;
    const int f0 = n0 + srow;
    const unsigned b0q = (unsigned)f0 / L_, l0q = (unsigned)f0 - b0q * L_;
    const int f1 = f0 + 64;
    const unsigned b1q = (unsigned)f1 / L_, l1q = (unsigned)f1 - b1q * L_;
    const unsigned short* Bg0 = Om + ((size_t)(b0q * HEADS_) * L_ + l0q) * N_ + skc;
    const unsigned short* Bg1 = Om + ((size_t)(b1q * HEADS_) * L_ + l1q) * N_ + skc;
    const size_t kstride = (size_t)L_ * N_;

    f32x4 acc[4][4];
#pragma unroll
    for (int m = 0; m < 4; ++m)
#pragma unroll
        for (int n = 0; n < 4; ++n) acc[m][n] = (f32x4){0.f, 0.f, 0.f, 0.f};

    {   // prologue
        char* An = (char*)&As[0][0] + w * 1024;
        char* Bn = (char*)&Bs[0][0] + w * 1024;
        GL2L(Ag, An);            GL2L(Ag + 64 * D_, An + 4096);
        GL2L(Bg0, Bn);           GL2L(Bg1, Bn + 4096);
    }
    __syncthreads();

#pragma unroll
    for (int kt = 0; kt < 8; ++kt) {
        const int cur = kt & 1;
        if (kt < 7) {
            const int c1 = (kt + 1) * 32;
            char* An = (char*)&As[cur ^ 1][0] + w * 1024;
            char* Bn = (char*)&Bs[cur ^ 1][0] + w * 1024;
            GL2L(Ag + c1, An);                     GL2L(Ag + 64 * D_ + c1, An + 4096);
            GL2L(Bg0 + (kt + 1) * kstride, Bn);    GL2L(Bg1 + (kt + 1) * kstride, Bn + 4096);
        }
        const unsigned short* Ab = &As[cur][0];
        const unsigned short* Bb = &Bs[cur][0];
        short8 af[4], bf[4];
#pragma unroll
        for (int m = 0; m < 4; ++m)
            af[m] = *(const short8*)(Ab + (wr * 64 + m * 16 + col) * 32 + quad * 8);
#pragma unroll
        for (int n = 0; n < 4; ++n)
            bf[n] = *(const short8*)(Bb + (wc * 64 + n * 16 + col) * 32 + quad * 8);
#pragma unroll
        for (int m = 0; m < 4; ++m)
#pragma unroll
            for (int n = 0; n < 4; ++n)
                acc[m][n] = __builtin_amdgcn_mfma_f32_16x16x32_bf16(af[m], bf[n], acc[m][n], 0, 0, 0);
        __syncthreads();
    }

#pragma unroll
    for (int n = 0; n < 4; ++n) {
        const unsigned flat = n0 + wc * 64 + n * 16 + col;
        const unsigned bq = flat / L_;
        const unsigned lq = flat - bq * L_;
        float* oout = Out + (size_t)bq * D_ * L_ + lq;
#pragma unroll
        for (int m = 0; m < 4; ++m) {
            const int dbase = d0 + wr * 64 + m * 16 + quad * 4;
#pragma unroll
            for (int r = 0; r < 4; ++r)
                oout[(size_t)(dbase + r) * L_] = acc[m][n][r];
        }
    }
}

// ---------------------------------------------------------------------------
extern "C" void kernel_launch(void* const* d_in, const int* in_sizes, int n_in,
                              void* d_out, int out_size, void* d_ws, size_t ws_size,
                              hipStream_t stream)
{
    const float* x       = (const float*)d_in[0];
    const float* q       = (const float*)d_in[1];
    const float* Wk      = (const float*)d_in[2];
    const float* Wv      = (const float*)d_in[3];
    const float* pos_emb = (const float*)d_in[4];
    const float* Wlin    = (const float*)d_in[5];
    const float* Wproj   = (const float*)d_in[6];
    float* out = (float*)d_out;

    const size_t planeE = (size_t)B_ * D_ * L_;
    unsigned short* Xt  = (unsigned short*)d_ws;
    unsigned short* Vo  = Xt + planeE;
    unsigned short* Om  = Vo + planeE;
    unsigned short* Wvb = Om + planeE;
    unsigned short* Wpb = Wvb + D_ * D_;
    float*          S   = (float*)(Wpb + D_ * D_);
    float*          qt  = S + (size_t)B_ * HEADS_ * L_;

    convert_w_kernel<<<dim3(64, 3), 256, 0, stream>>>(Wv, Wproj, Wk, q, Wvb, Wpb, qt);
    transpose_x_kernel<<<dim3(L_ / 64, D_ / 64, B_), 256, 0, stream>>>(x, Xt);
    s_kernel<<<dim3((L_ + 255) / 256, B_), 256, 0, stream>>>(x, qt, S);
    gemm_v_mfma<<<dim3(BL_ / 128, 2), 256, 0, stream>>>(Xt, Wvb, Vo);
    attend_kernel<<<dim3(7, B_ * HEADS_), 256, 0, stream>>>(S, Vo, pos_emb, Wlin, Om);
    gemm_proj_mfma<<<dim3(BL_ / 128, 2), 256, 0, stream>>>(Om, Wpb, out);
}

// Round 4
// 174.601 us; speedup vs baseline: 1.1235x; 1.0152x over previous
//
#include <hip/hip_runtime.h>

#define B_     16
#define D_     256
#define HEADS_ 8
#define N_     32
#define H_     56
#define W_     56
#define L_     3136
#define BL_    (B_ * L_)   // 50176 flattened (b,l) columns
#define LDA_A  264         // A-tile LDS row stride: 16B-aligned rows, even bank spread

typedef short short8 __attribute__((ext_vector_type(8)));
typedef float f32x4  __attribute__((ext_vector_type(4)));

__device__ __forceinline__ unsigned short f2bf(float f) {
    union { float f; unsigned u; } c; c.f = f;
    unsigned u = c.u;
    u += 0x7fffu + ((u >> 16) & 1u);   // RNE
    return (unsigned short)(u >> 16);
}

// ---------------------------------------------------------------------------
// Wv, Wproj fp32 -> bf16; blockIdx.y==2 computes q~[b,h,c] = sum_n q[b,hn]*Wk[hn,c]
// ---------------------------------------------------------------------------
__global__ __launch_bounds__(256) void convert_w_kernel(
    const float* __restrict__ Wv, const float* __restrict__ Wproj,
    const float* __restrict__ Wk, const float* __restrict__ q,
    unsigned short* __restrict__ Wvb, unsigned short* __restrict__ Wpb,
    float* __restrict__ qt)
{
    if (blockIdx.y < 2) {
        const float* src   = (blockIdx.y == 0) ? Wv  : Wproj;
        unsigned short* dst = (blockIdx.y == 0) ? Wvb : Wpb;
        const int i = (blockIdx.x * 256 + threadIdx.x) * 4;
        float4 v = *(const float4*)(src + i);
        uint2 o;
        o.x = (unsigned)f2bf(v.x) | ((unsigned)f2bf(v.y) << 16);
        o.y = (unsigned)f2bf(v.z) | ((unsigned)f2bf(v.w) << 16);
        *(uint2*)(dst + i) = o;
    } else {
        const int b  = blockIdx.x >> 2;
        const int h0 = (blockIdx.x & 3) * 2;
        const int c  = threadIdx.x;
#pragma unroll
        for (int hh = 0; hh < 2; ++hh) {
            const int h = h0 + hh;
            const float* qb = q  + b * D_ + h * N_;
            const float* wr = Wk + (size_t)(h * N_) * D_ + c;
            float acc = 0.f;
#pragma unroll 8
            for (int n = 0; n < N_; ++n)
                acc = fmaf(qb[n], wr[(size_t)n * D_], acc);
            qt[((size_t)b * HEADS_ + h) * D_ + c] = acc;
        }
    }
}

// ---------------------------------------------------------------------------
// S[b,h,l] = sum_c q~[b,h,c] * x[b,c,l].  Block covers 128 l (32 float4 lanes)
// x 8 c-groups of 32; 400 blocks. Runs FIRST so x is L2/L3-hot for gemm_v.
// ---------------------------------------------------------------------------
__global__ __launch_bounds__(256) void s_kernel(
    const float* __restrict__ x, const float* __restrict__ qt,
    float* __restrict__ S)
{
    __shared__ float  qs[HEADS_ * D_];       // 8 KB
    __shared__ float4 red[8][HEADS_][32];    // 32 KB

    const int bb = blockIdx.y;
    const int l0 = blockIdx.x * 128;
    const int t  = threadIdx.x;
    const int lg = t & 31;      // float4 group within 128 l
    const int cg = t >> 5;      // c-group (32 channels each)

    {
        const float4* s4 = (const float4*)(qt + (size_t)bb * HEADS_ * D_);
        ((float4*)qs)[t]       = s4[t];
        ((float4*)qs)[t + 256] = s4[t + 256];
    }
    __syncthreads();

    float4 sacc[8];
#pragma unroll
    for (int h = 0; h < 8; ++h) sacc[h] = (float4){0.f, 0.f, 0.f, 0.f};

    const int l = l0 + lg * 4;
    if (l < L_) {
        const float* xb = x + (size_t)bb * D_ * L_ + l;
#pragma unroll 4
        for (int c = cg * 32; c < cg * 32 + 32; ++c) {
            const float4 xv = *(const float4*)(xb + (size_t)c * L_);
#pragma unroll
            for (int h = 0; h < 8; ++h) {
                const float qv = qs[h * D_ + c];
                sacc[h].x = fmaf(qv, xv.x, sacc[h].x);
                sacc[h].y = fmaf(qv, xv.y, sacc[h].y);
                sacc[h].z = fmaf(qv, xv.z, sacc[h].z);
                sacc[h].w = fmaf(qv, xv.w, sacc[h].w);
            }
        }
    }

#pragma unroll
    for (int h = 0; h < 8; ++h) red[cg][h][lg] = sacc[h];
    __syncthreads();

    {
        const int h  = t >> 5;
        const int l2 = t & 31;
        const int lw = l0 + l2 * 4;
        if (lw < L_) {
            float4 o = (float4){0.f, 0.f, 0.f, 0.f};
#pragma unroll
            for (int g = 0; g < 8; ++g) {
                const float4 v = red[g][h][l2];
                o.x += v.x; o.y += v.y; o.z += v.z; o.w += v.w;
            }
            *(float4*)(S + ((size_t)bb * HEADS_ + h) * L_ + lw) = o;
        }
    }
}

// ---------------------------------------------------------------------------
// V = Wv @ x, barrier-free K-loop. A (Wv bf16) staged ONCE in padded LDS;
// B fragments gathered straight from fp32 x (8 dword loads + 4 cvt_pk per
// frag), so no transpose kernel / Xt buffer / per-step barriers exist.
// Output Vo[b][h][l][32] (uint2 stores).
// ---------------------------------------------------------------------------
__global__ __launch_bounds__(256) void gemm_v_mfma(
    const float* __restrict__ x, const unsigned short* __restrict__ Wvb,
    unsigned short* __restrict__ Vo)
{
    __shared__ __align__(16) unsigned short As[128 * LDA_A];   // 66 KB

    const int t = threadIdx.x;
    const int w = t >> 6, lane = t & 63, col = lane & 15, quad = lane >> 4;
    const int wr = w >> 1, wc = w & 1;
    const int n0 = blockIdx.x * 128;
    const int d0 = blockIdx.y * 128;

    // ---- one-shot A stage: 128 rows x 256 c ----
#pragma unroll
    for (int i = 0; i < 16; ++i) {
        const int u   = t + i * 256;       // uint4 index
        const int row = u >> 5;            // 32 uint4 per row
        const int cu  = (u & 31) * 8;
        uint4 v = *(const uint4*)(Wvb + (size_t)(d0 + row) * D_ + cu);
        *(uint4*)&As[row * LDA_A + cu] = v;
    }

    // ---- per-lane B base pointers (flat b*l handled per lane) ----
    const float* xb[4];
#pragma unroll
    for (int n = 0; n < 4; ++n) {
        const unsigned flat = n0 + wc * 64 + n * 16 + col;
        const unsigned bq = flat / L_;
        const unsigned lq = flat - bq * L_;
        xb[n] = x + ((size_t)bq * D_ + quad * 8) * L_ + lq;
    }

    f32x4 acc[4][4];
#pragma unroll
    for (int m = 0; m < 4; ++m)
#pragma unroll
        for (int n = 0; n < 4; ++n) acc[m][n] = (f32x4){0.f, 0.f, 0.f, 0.f};

    __syncthreads();

#pragma unroll
    for (int kt = 0; kt < 8; ++kt) {
        short8 bf[4];
#pragma unroll
        for (int n = 0; n < 4; ++n) {
            float f[8];
#pragma unroll
            for (int j = 0; j < 8; ++j)
                f[j] = xb[n][(size_t)(kt * 32 + j) * L_];
            union { unsigned u[4]; short8 s; } pk;
#pragma unroll
            for (int p = 0; p < 4; ++p)
                asm("v_cvt_pk_bf16_f32 %0, %1, %2"
                    : "=v"(pk.u[p]) : "v"(f[2 * p]), "v"(f[2 * p + 1]));
            bf[n] = pk.s;
        }
        short8 af[4];
#pragma unroll
        for (int m = 0; m < 4; ++m)
            af[m] = *(const short8*)&As[(wr * 64 + m * 16 + col) * LDA_A + kt * 32 + quad * 8];
#pragma unroll
        for (int m = 0; m < 4; ++m)
#pragma unroll
            for (int n = 0; n < 4; ++n)
                acc[m][n] = __builtin_amdgcn_mfma_f32_16x16x32_bf16(af[m], bf[n], acc[m][n], 0, 0, 0);
    }

#pragma unroll
    for (int n = 0; n < 4; ++n) {
        const unsigned flat = n0 + wc * 64 + n * 16 + col;
        const unsigned bq = flat / L_;
        const unsigned lq = flat - bq * L_;
#pragma unroll
        for (int m = 0; m < 4; ++m) {
            const int d  = d0 + wr * 64 + m * 16 + quad * 4;
            const int h  = d >> 5;
            const int dn = d & 31;
            unsigned short ob[4];
#pragma unroll
            for (int r = 0; r < 4; ++r) ob[r] = f2bf(acc[m][n][r]);
            *(uint2*)(Vo + ((size_t)(bq * HEADS_ + h) * L_ + lq) * N_ + dn) =
                *(const uint2*)ob;
        }
    }
}

// ---------------------------------------------------------------------------
// attend v4 (verified): block = (8-row band, b*h), all 32 channels.
// V staged as 600 positions x 64B in LDS with XOR chunk swizzle.
// ---------------------------------------------------------------------------
__global__ __launch_bounds__(256) void attend_kernel(
    const float* __restrict__ S, const unsigned short* __restrict__ Vo,
    const float* __restrict__ pos_emb, const float* __restrict__ Wlin,
    unsigned short* __restrict__ Om)
{
    __shared__ __align__(16) unsigned short Vs[600 * 32];  // 37.5 KB swizzled
    __shared__ float Ss[10][58];                           // 2.3 KB

    const int band = blockIdx.x;   // 0..6
    const int bh   = blockIdx.y;   // 0..127
    const int y0   = band * 8;
    const int t    = threadIdx.x;

    const float* Sb = S + (size_t)bh * L_;
    for (int wi = t; wi < 580; wi += 256) {
        const int row = wi / 58, c = wi - row * 58;
        const int gr = y0 - 1 + row, gc = c - 1;
        float v = 0.f;
        if (gr >= 0 && gr < H_ && gc >= 0 && gc < W_)
            v = Sb[gr * W_ + gc];
        Ss[row][c] = v;
    }

    const unsigned short* Vbase = Vo + (size_t)bh * L_ * N_;
    for (int wi = t; wi < 2400; wi += 256) {
        const int p = wi >> 2, i = wi & 3;
        const int row = p / 60, cc = p - row * 60;
        const int gr = y0 - 1 + row, gc = cc - 1;
        uint4 v = make_uint4(0u, 0u, 0u, 0u);
        if (gr >= 0 && gr < H_ && gc >= 0 && gc < W_)
            v = *(const uint4*)(Vbase + (size_t)(gr * W_ + gc) * N_ + i * 8);
        const int sfc = wi ^ (p & 7);          // swizzled 16B-chunk index
        *(uint4*)(Vs + sfc * 8) = v;
    }
    __syncthreads();

    const float scale = Wlin[0] + Wlin[1] + Wlin[2] + Wlin[3];
    const float pe0 = pos_emb[0], pe1 = pos_emb[1], pe2 = pos_emb[2];
    const float pe3 = pos_emb[3], pe4 = pos_emb[4];
    const float bias[9] = {pe0, pe1, pe2, pe1, pe2, pe3, pe2, pe3, pe4};

    for (int idx = t; idx < 448; idx += 256) {
        const int yl = idx / 56, xx = idx - yl * 56;
        const int lr = yl + 1, lc = xx + 1;

        float lg[9], m = -1e30f;
#pragma unroll
        for (int dy = 0; dy < 3; ++dy)
#pragma unroll
            for (int dx = 0; dx < 3; ++dx) {
                const int k = dy * 3 + dx;
                lg[k] = Ss[lr - 1 + dy][lc - 1 + dx] + bias[k];
                m = fmaxf(m, lg[k]);
            }
        float ssum = 0.f;
#pragma unroll
        for (int k = 0; k < 9; ++k) { lg[k] = __expf(lg[k] - m); ssum += lg[k]; }
        const float inv = scale / ssum;

        float om[32];
#pragma unroll
        for (int i = 0; i < 32; ++i) om[i] = 0.f;

#pragma unroll
        for (int dy = 0; dy < 3; ++dy)
#pragma unroll
            for (int dx = 0; dx < 3; ++dx) {
                const float wk = lg[dy * 3 + dx] * inv;
                const int pos  = (lr - 1 + dy) * 60 + (lc - 1 + dx);
                const int base = pos * 4;
                const int msk  = pos & 7;
#pragma unroll
                for (int i = 0; i < 4; ++i) {
                    const int sfc = (base + i) ^ msk;
                    const uint4 v = *(const uint4*)(Vs + sfc * 8);
                    const unsigned* u = (const unsigned*)&v;
#pragma unroll
                    for (int j = 0; j < 4; ++j) {
                        union { unsigned uu; float f; } lo, hi;
                        lo.uu = u[j] << 16;
                        hi.uu = u[j] & 0xffff0000u;
                        om[i * 8 + 2 * j]     = fmaf(wk, lo.f, om[i * 8 + 2 * j]);
                        om[i * 8 + 2 * j + 1] = fmaf(wk, hi.f, om[i * 8 + 2 * j + 1]);
                    }
                }
            }

        unsigned short ob[32];
#pragma unroll
        for (int i = 0; i < 32; ++i) ob[i] = f2bf(om[i]);
        const int l = (y0 + yl) * W_ + xx;
        uint4* dst = (uint4*)(Om + ((size_t)bh * L_ + l) * N_);
        const uint4* sb = (const uint4*)ob;
#pragma unroll
        for (int i = 0; i < 4; ++i) dst[i] = sb[i];
    }
}

// ---------------------------------------------------------------------------
// out = Wproj @ Om, barrier-free K-loop. A (Wproj) one-shot in LDS;
// B fragment = single dwordx4 from Om[b][h][l][32] (K contiguous per head).
// ---------------------------------------------------------------------------
__global__ __launch_bounds__(256) void gemm_proj_mfma(
    const unsigned short* __restrict__ Om, const unsigned short* __restrict__ Wpb,
    float* __restrict__ Out)
{
    __shared__ __align__(16) unsigned short As[128 * LDA_A];   // 66 KB

    const int t = threadIdx.x;
    const int w = t >> 6, lane = t & 63, col = lane & 15, quad = lane >> 4;
    const int wr = w >> 1, wc = w & 1;
    const int n0 = blockIdx.x * 128;
    const int d0 = blockIdx.y * 128;

    // ---- one-shot A stage ----
#pragma unroll
    for (int i = 0; i < 16; ++i) {
        const int u   = t + i * 256;
        const int row = u >> 5;
        const int cu  = (u & 31) * 8;
        uint4 v = *(const uint4*)(Wpb + (size_t)(d0 + row) * D_ + cu);
        *(uint4*)&As[row * LDA_A + cu] = v;
    }

    // ---- per-lane B base pointers ----
    const unsigned short* ob[4];
#pragma unroll
    for (int n = 0; n < 4; ++n) {
        const unsigned flat = n0 + wc * 64 + n * 16 + col;
        const unsigned bq = flat / L_;
        const unsigned lq = flat - bq * L_;
        ob[n] = Om + ((size_t)(bq * HEADS_) * L_ + lq) * N_ + quad * 8;
    }
    const size_t kstride = (size_t)L_ * N_;

    f32x4 acc[4][4];
#pragma unroll
    for (int m = 0; m < 4; ++m)
#pragma unroll
        for (int n = 0; n < 4; ++n) acc[m][n] = (f32x4){0.f, 0.f, 0.f, 0.f};

    __syncthreads();

#pragma unroll
    for (int kt = 0; kt < 8; ++kt) {
        short8 bf[4], af[4];
#pragma unroll
        for (int n = 0; n < 4; ++n)
            bf[n] = *(const short8*)(ob[n] + (size_t)kt * kstride);
#pragma unroll
        for (int m = 0; m < 4; ++m)
            af[m] = *(const short8*)&As[(wr * 64 + m * 16 + col) * LDA_A + kt * 32 + quad * 8];
#pragma unroll
        for (int m = 0; m < 4; ++m)
#pragma unroll
            for (int n = 0; n < 4; ++n)
                acc[m][n] = __builtin_amdgcn_mfma_f32_16x16x32_bf16(af[m], bf[n], acc[m][n], 0, 0, 0);
    }

#pragma unroll
    for (int n = 0; n < 4; ++n) {
        const unsigned flat = n0 + wc * 64 + n * 16 + col;
        const unsigned bq = flat / L_;
        const unsigned lq = flat - bq * L_;
        float* oout = Out + (size_t)bq * D_ * L_ + lq;
#pragma unroll
        for (int m = 0; m < 4; ++m) {
            const int dbase = d0 + wr * 64 + m * 16 + quad * 4;
#pragma unroll
            for (int r = 0; r < 4; ++r)
                oout[(size_t)(dbase + r) * L_] = acc[m][n][r];
        }
    }
}

// ---------------------------------------------------------------------------
extern "C" void kernel_launch(void* const* d_in, const int* in_sizes, int n_in,
                              void* d_out, int out_size, void* d_ws, size_t ws_size,
                              hipStream_t stream)
{
    const float* x       = (const float*)d_in[0];
    const float* q       = (const float*)d_in[1];
    const float* Wk      = (const float*)d_in[2];
    const float* Wv      = (const float*)d_in[3];
    const float* pos_emb = (const float*)d_in[4];
    const float* Wlin    = (const float*)d_in[5];
    const float* Wproj   = (const float*)d_in[6];
    float* out = (float*)d_out;

    const size_t planeE = (size_t)B_ * D_ * L_;
    unsigned short* Vo  = (unsigned short*)d_ws;
    unsigned short* Om  = Vo + planeE;
    unsigned short* Wvb = Om + planeE;
    unsigned short* Wpb = Wvb + D_ * D_;
    float*          S   = (float*)(Wpb + D_ * D_);
    float*          qt  = S + (size_t)B_ * HEADS_ * L_;

    convert_w_kernel<<<dim3(64, 3), 256, 0, stream>>>(Wv, Wproj, Wk, q, Wvb, Wpb, qt);
    s_kernel<<<dim3((L_ + 127) / 128, B_), 256, 0, stream>>>(x, qt, S);
    gemm_v_mfma<<<dim3(BL_ / 128, 2), 256, 0, stream>>>(x, Wvb, Vo);
    attend_kernel<<<dim3(7, B_ * HEADS_), 256, 0, stream>>>(S, Vo, pos_emb, Wlin, Om);
    gemm_proj_mfma<<<dim3(BL_ / 128, 2), 256, 0, stream>>>(Om, Wpb, out);
}